// Round 13
// baseline (230.426 us; speedup 1.0000x reference)
//
#include <hip/hip_runtime.h>
#include <hip/hip_bf16.h>

#define WAVE 64
typedef unsigned int uint32;
typedef __attribute__((ext_vector_type(8))) short bf16x8;
typedef __attribute__((ext_vector_type(4))) float f32x4;
typedef __attribute__((ext_vector_type(2))) float f32x2;

// ---- bf16 helpers ----
__device__ inline uint32 f2bf(float f) {  // round-to-nearest-even, bits in low 16
    union { float f; uint32 u; } a; a.f = f;
    uint32 u = a.u;
    u += 0x7fffu + ((u >> 16) & 1u);
    return u >> 16;
}
__device__ inline uint32 packbf(float lo, float hi) { return f2bf(lo) | (f2bf(hi) << 16); }
__device__ inline f32x2 shflx(f32x2 v, int o) {
    v.x = __shfl_xor(v.x, o, WAVE);
    v.y = __shfl_xor(v.y, o, WAVE);
    return v;
}
// ---- fp8 e4m3 helpers (HW cvt, OCP on gfx950) ----
template <bool HI>
__device__ inline f32x2 up8(uint32 u) {  // bytes (0,1) or (2,3) -> {lo, hi} f32
    return __builtin_amdgcn_cvt_pk_f32_fp8((int)u, HI);
}
__device__ inline unsigned short pack8(float lo, float hi) {
    return (unsigned short)__builtin_amdgcn_cvt_pk_fp8_f32(lo, hi, 0, false);
}

// ---------------- W1/W2 -> fragment-ordered bf16 (+ gcnt zeroing) ----------------
__global__ void convert_w_kernel(const float* __restrict__ W1, const float* __restrict__ W2,
                                 uint32* __restrict__ w1f, uint32* __restrict__ w2f,
                                 int* __restrict__ gcnt) {
    int tid = blockIdx.x * blockDim.x + threadIdx.x;  // 0..20479
    if (tid < 512) gcnt[tid] = 0;
    if (tid < 16384) {
        int w = tid & 3, l = (tid >> 2) & 63, c = (tid >> 8) & 7, kc = tid >> 11;
        int q = l & 15, g = l >> 4;
        int k0 = kc * 32 + g * 8 + 2 * w;
        int n = c * 16 + q;
        w1f[tid] = packbf(W1[k0 * 128 + n], W1[(k0 + 1) * 128 + n]);
    } else if (tid < 16384 + 4096) {
        int t = tid - 16384;
        int w = t & 3, l = (t >> 2) & 63, c = (t >> 8) & 3, kc = t >> 10;
        int q = l & 15, g = l >> 4;
        int k0 = kc * 32 + g * 8 + 2 * w;
        int n = c * 16 + q;
        w2f[t] = packbf(W2[k0 * 64 + n], W2[(k0 + 1) * 64 + n]);
    }
}

// ================= CSR build: two-pass bucket sort, 256-node buckets =================
// Bucket = dst >> 8. NBUCK <= 512. pairs pack: src (17b) | dstLow (8b) << 17.
#define BIN_TB 1024
#define BIN_EPB 4096
__global__ __launch_bounds__(BIN_TB) void binsort_kernel(const int* __restrict__ src,
                                                         const int* __restrict__ dst,
                                                         int* __restrict__ gcnt,
                                                         uint32* __restrict__ pairs,
                                                         int E, int CAP) {
    __shared__ int hist[512];
    __shared__ int scan[512];
    __shared__ int lstart[512];
    __shared__ int gbase[512];
    __shared__ int lcur[512];
    __shared__ uint32 sp[BIN_EPB];
    __shared__ unsigned short sb[BIN_EPB];
    int tid = threadIdx.x;
    int base = blockIdx.x * BIN_EPB;
    if (tid < 512) hist[tid] = 0;
    __syncthreads();
    int b[4];
    uint32 pk[4];
    bool v[4];
#pragma unroll
    for (int j = 0; j < 4; ++j) {
        int e = base + tid + j * BIN_TB;
        v[j] = e < E;
        if (v[j]) {
            int s = src[e];
            int d = dst[e];
            b[j] = d >> 8;
            pk[j] = (uint32)s | ((uint32)(d & 255) << 17);
            atomicAdd(&hist[b[j]], 1);
        }
    }
    __syncthreads();
    if (tid < 512) scan[tid] = hist[tid];
    __syncthreads();
#pragma unroll
    for (int o = 1; o < 512; o <<= 1) {
        int t = 0;
        if (tid < 512 && tid >= o) t = scan[tid - o];
        __syncthreads();
        if (tid < 512) scan[tid] += t;
        __syncthreads();
    }
    if (tid < 512) {
        int st = scan[tid] - hist[tid];
        lstart[tid] = st;
        lcur[tid] = st;
        gbase[tid] = (hist[tid] > 0) ? (tid * CAP + atomicAdd(&gcnt[tid], hist[tid])) : 0;
    }
    __syncthreads();
#pragma unroll
    for (int j = 0; j < 4; ++j) {
        if (v[j]) {
            int p = atomicAdd(&lcur[b[j]], 1);
            sp[p] = pk[j];
            sb[p] = (unsigned short)b[j];
        }
    }
    __syncthreads();
    int total = scan[511];
    for (int i = tid; i < total; i += BIN_TB) {
        int bb = sb[i];
        pairs[gbase[bb] + (i - lstart[bb])] = sp[i];
    }
}

// Pass C: per-bucket (256 nodes) counting sort staged in dynamic LDS, coalesced flush.
__global__ __launch_bounds__(1024) void bucket_csr_kernel(const uint32* __restrict__ pairs,
                                                          const int* __restrict__ gcnt,
                                                          int* __restrict__ sorted,
                                                          int* __restrict__ rowstart,
                                                          int* __restrict__ rowend,
                                                          float* __restrict__ dinv,
                                                          int N, int CAP) {
    __shared__ int cnt[256];
    __shared__ int incl[256];
    __shared__ int cursor[256];
    extern __shared__ uint32 ssorted[];  // CAP entries
    int b = blockIdx.x;
    int tid = threadIdx.x;
    int ne = gcnt[b];
    if (ne > CAP) ne = CAP;
    const uint32* P = pairs + (size_t)b * CAP;
    if (tid < 256) cnt[tid] = 0;
    __syncthreads();
    for (int i = tid; i < ne; i += 1024) atomicAdd(&cnt[P[i] >> 17], 1);
    __syncthreads();
    int v = 0;
    if (tid < 256) { v = cnt[tid]; incl[tid] = v; }
    __syncthreads();
#pragma unroll
    for (int o = 1; o < 256; o <<= 1) {
        int t = 0;
        if (tid < 256 && tid >= o) t = incl[tid - o];
        __syncthreads();
        if (tid < 256) incl[tid] += t;
        __syncthreads();
    }
    int gbase = b * CAP;
    if (tid < 256) {
        int node = b * 256 + tid;
        if (node < N) {
            rowstart[node] = gbase + incl[tid] - v;
            rowend[node] = gbase + incl[tid];
            dinv[node] = rsqrtf(1.0f + (float)v);
        }
        cursor[tid] = incl[tid] - v;
    }
    __syncthreads();
    for (int i = tid; i < ne; i += 1024) {
        uint32 p = P[i];
        int ln = p >> 17;
        int r = atomicAdd(&cursor[ln], 1);
        ssorted[r] = p & 0x1FFFFu;
    }
    __syncthreads();
    for (int i = tid; i < ne; i += 1024) sorted[gbase + i] = (int)ssorted[i];
}

// ---------------- GEMM1 (MFMA, LDS-staged): [N,256]fp32 @ W1F -> h1f fp8 ----------------
// Per kc: stage 128 rows x 32 k-floats as bf16 into LDS (coalesced global loads),
// A fragment = one ds_read_b128. LDS row stride 40 bf16 (80 B, 16B-aligned frags).
__global__ __launch_bounds__(256) void gemm1_mfma(const float* __restrict__ x,
                                                  const uint32* __restrict__ w1f,
                                                  const float* __restrict__ dinv,
                                                  unsigned short* __restrict__ h1f,  // N x 64 u16
                                                  int N) {
    __shared__ short xs[128 * 40];  // 10 KB
    const bf16x8* Bp = (const bf16x8*)w1f;
    int tid = threadIdx.x;
    int l = tid & 63, w = tid >> 6;
    int q = l & 15, g = l >> 4;
    int R = blockIdx.x * 128;
    int rloc = w * 32;
    f32x4 acc[2][8];
#pragma unroll
    for (int rt = 0; rt < 2; ++rt)
#pragma unroll
        for (int c = 0; c < 8; ++c) acc[rt][c] = (f32x4){0.f, 0.f, 0.f, 0.f};

    int srow = tid >> 1;
    int scol = (tid & 1) * 16;
    long grow_s = R + srow;
    if (grow_s > N - 1) grow_s = N - 1;
    const float* xbase = x + grow_s * 256 + scol;
    uint2* sdst = (uint2*)&xs[srow * 40 + scol];

#pragma unroll
    for (int kc = 0; kc < 8; ++kc) {
        __syncthreads();
        {
            const float4* xp = (const float4*)(xbase + kc * 32);
            float4 f0 = xp[0], f1 = xp[1], f2 = xp[2], f3 = xp[3];
            sdst[0] = make_uint2(packbf(f0.x, f0.y), packbf(f0.z, f0.w));
            sdst[1] = make_uint2(packbf(f1.x, f1.y), packbf(f1.z, f1.w));
            sdst[2] = make_uint2(packbf(f2.x, f2.y), packbf(f2.z, f2.w));
            sdst[3] = make_uint2(packbf(f3.x, f3.y), packbf(f3.z, f3.w));
        }
        __syncthreads();
        bf16x8 b[8];
#pragma unroll
        for (int c = 0; c < 8; ++c) b[c] = Bp[(kc * 8 + c) * 64 + l];
#pragma unroll
        for (int rt = 0; rt < 2; ++rt) {
            bf16x8 a = *(const bf16x8*)&xs[(rloc + rt * 16 + q) * 40 + g * 8];
#pragma unroll
            for (int c = 0; c < 8; ++c)
                acc[rt][c] = __builtin_amdgcn_mfma_f32_16x16x32_bf16(a, b[c], acc[rt][c], 0, 0, 0);
        }
    }
#pragma unroll
    for (int rt = 0; rt < 2; ++rt)
#pragma unroll
        for (int r = 0; r < 4; ++r) {
            int grow = R + rloc + rt * 16 + 4 * g + r;
            if (grow < N) {
                float wd = dinv[grow];
                unsigned short* orow = h1f + (size_t)grow * 64;
#pragma unroll
                for (int c = 0; c < 4; ++c)
                    orow[c * 16 + q] = pack8(acc[rt][c][r] * wd, acc[rt][c + 4][r] * wd);
            }
        }
}

// ---------------- layer-1 pull aggregation: lane-owns-slot, 8 edges in flight ----------------
__global__ __launch_bounds__(256) void agg1_kernel(const uint32* __restrict__ h1,  // N x 32 u32
                                                   const float* __restrict__ dinv,
                                                   const int* __restrict__ srt,
                                                   const int* __restrict__ rowstart,
                                                   const int* __restrict__ rowend,
                                                   const float* __restrict__ bias,
                                                   uint32* __restrict__ out,  // N x 64
                                                   int n) {
    int wid = (int)(((long)blockIdx.x * blockDim.x + threadIdx.x) >> 6);
    int lane = threadIdx.x & 63;
    if (wid >= n) return;
    int q = lane & 31;
    int half = lane >> 5;
    int start = rowstart[wid];
    int end = rowend[wid];
    f32x2 aL = {0.f, 0.f}, aH = {0.f, 0.f};
    if (half == 0) {  // self (already dinv-scaled)
        uint32 u = h1[(size_t)wid * 32 + q];
        aL = up8<false>(u); aH = up8<true>(u);
    }
    int e = start + half;
    for (; e + 14 < end; e += 16) {  // 8 edges in flight per half-wave
        int s0 = srt[e], s1 = srt[e + 2], s2 = srt[e + 4], s3 = srt[e + 6];
        int s4 = srt[e + 8], s5 = srt[e + 10], s6 = srt[e + 12], s7 = srt[e + 14];
        uint32 u0 = h1[(size_t)s0 * 32 + q];
        uint32 u1 = h1[(size_t)s1 * 32 + q];
        uint32 u2 = h1[(size_t)s2 * 32 + q];
        uint32 u3 = h1[(size_t)s3 * 32 + q];
        uint32 u4 = h1[(size_t)s4 * 32 + q];
        uint32 u5 = h1[(size_t)s5 * 32 + q];
        uint32 u6 = h1[(size_t)s6 * 32 + q];
        uint32 u7 = h1[(size_t)s7 * 32 + q];
        aL += up8<false>(u0); aH += up8<true>(u0);
        aL += up8<false>(u1); aH += up8<true>(u1);
        aL += up8<false>(u2); aH += up8<true>(u2);
        aL += up8<false>(u3); aH += up8<true>(u3);
        aL += up8<false>(u4); aH += up8<true>(u4);
        aL += up8<false>(u5); aH += up8<true>(u5);
        aL += up8<false>(u6); aH += up8<true>(u6);
        aL += up8<false>(u7); aH += up8<true>(u7);
    }
    for (; e < end; e += 2) {
        uint32 u = h1[(size_t)srt[e] * 32 + q];
        aL += up8<false>(u); aH += up8<true>(u);
    }
    aL += shflx(aL, 32);
    aH += shflx(aH, 32);
    if (half == 0) {
        float wd = dinv[wid];
        float2 b0 = ((const float2*)bias)[q];        // b[2q], b[2q+1]
        float2 b1 = ((const float2*)bias)[q + 32];   // b[2q+64], b[2q+65]
        float v0 = fmaxf(fmaf(wd, aL.x, b0.x), 0.f); // f2q
        float v1 = fmaxf(fmaf(wd, aH.x, b0.y), 0.f); // f2q+1
        float v2 = fmaxf(fmaf(wd, aL.y, b1.x), 0.f); // f2q+64
        float v3 = fmaxf(fmaf(wd, aH.y, b1.y), 0.f); // f2q+65
        uint32* orow = out + (size_t)wid * 64;
        orow[q] = packbf(v0, v1);
        orow[32 + q] = packbf(v2, v3);
    }
}

// ---------------- GEMM2 (MFMA): [N,128]bf16 @ W2F -> h2f fp8, u16 slot j = (f_j, f_j+32) ----------------
__global__ __launch_bounds__(256) void gemm2_mfma(const uint32* __restrict__ hin,  // N x 64 bf16-pairs
                                                  const uint32* __restrict__ w2f,
                                                  const float* __restrict__ dinv,
                                                  unsigned short* __restrict__ h2f,  // N x 32 u16
                                                  int N) {
    const bf16x8* Bp = (const bf16x8*)w2f;
    const short* hs = (const short*)hin;
    int l = threadIdx.x & 63, w = threadIdx.x >> 6;
    int q = l & 15, g = l >> 4;
    int R = blockIdx.x * 128 + w * 32;
    f32x4 acc[2][4];
#pragma unroll
    for (int rt = 0; rt < 2; ++rt)
#pragma unroll
        for (int c = 0; c < 4; ++c) acc[rt][c] = (f32x4){0.f, 0.f, 0.f, 0.f};

#pragma unroll
    for (int kc = 0; kc < 4; ++kc) {
        bf16x8 b[4];
#pragma unroll
        for (int c = 0; c < 4; ++c) b[c] = Bp[(kc * 4 + c) * 64 + l];
#pragma unroll
        for (int rt = 0; rt < 2; ++rt) {
            int row = R + rt * 16 + q;
            row = row < N ? row : N - 1;
            bf16x8 a = *(const bf16x8*)(hs + (size_t)row * 128 + kc * 32 + g * 8);
#pragma unroll
            for (int c = 0; c < 4; ++c)
                acc[rt][c] = __builtin_amdgcn_mfma_f32_16x16x32_bf16(a, b[c], acc[rt][c], 0, 0, 0);
        }
    }
#pragma unroll
    for (int rt = 0; rt < 2; ++rt)
#pragma unroll
        for (int r = 0; r < 4; ++r) {
            int grow = R + rt * 16 + 4 * g + r;
            if (grow < N) {
                float wd = dinv[grow];
                unsigned short* orow = h2f + (size_t)grow * 32;
#pragma unroll
                for (int c = 0; c < 2; ++c)
                    orow[c * 16 + q] = pack8(acc[rt][c][r] * wd, acc[rt][c + 2][r] * wd);
            }
        }
}

// ---------------- layer-2 pull aggregation + log_softmax: lane-owns-slot, 8 in flight ----------------
__global__ __launch_bounds__(256) void agg2_ls_kernel(const uint32* __restrict__ h2,  // N x 16 u32
                                                      const float* __restrict__ dinv,
                                                      const int* __restrict__ srt,
                                                      const int* __restrict__ rowstart,
                                                      const int* __restrict__ rowend,
                                                      const float* __restrict__ bias,
                                                      float* __restrict__ out, int n) {
    int wid = (int)(((long)blockIdx.x * blockDim.x + threadIdx.x) >> 6);
    int lane = threadIdx.x & 63;
    if (wid >= n) return;
    int q = lane & 15;
    int g = lane >> 4;
    int start = rowstart[wid];
    int end = rowend[wid];
    f32x2 aL = {0.f, 0.f}, aH = {0.f, 0.f};
    if (g == 0) {  // self
        uint32 u = h2[(size_t)wid * 16 + q];
        aL = up8<false>(u); aH = up8<true>(u);
    }
    int e = start + g;
    for (; e + 28 < end; e += 32) {  // 8 edges in flight per group
        int s0 = srt[e], s1 = srt[e + 4], s2 = srt[e + 8], s3 = srt[e + 12];
        int s4 = srt[e + 16], s5 = srt[e + 20], s6 = srt[e + 24], s7 = srt[e + 28];
        uint32 u0 = h2[(size_t)s0 * 16 + q];
        uint32 u1 = h2[(size_t)s1 * 16 + q];
        uint32 u2 = h2[(size_t)s2 * 16 + q];
        uint32 u3 = h2[(size_t)s3 * 16 + q];
        uint32 u4 = h2[(size_t)s4 * 16 + q];
        uint32 u5 = h2[(size_t)s5 * 16 + q];
        uint32 u6 = h2[(size_t)s6 * 16 + q];
        uint32 u7 = h2[(size_t)s7 * 16 + q];
        aL += up8<false>(u0); aH += up8<true>(u0);
        aL += up8<false>(u1); aH += up8<true>(u1);
        aL += up8<false>(u2); aH += up8<true>(u2);
        aL += up8<false>(u3); aH += up8<true>(u3);
        aL += up8<false>(u4); aH += up8<true>(u4);
        aL += up8<false>(u5); aH += up8<true>(u5);
        aL += up8<false>(u6); aH += up8<true>(u6);
        aL += up8<false>(u7); aH += up8<true>(u7);
    }
    for (; e < end; e += 4) {
        uint32 u = h2[(size_t)srt[e] * 16 + q];
        aL += up8<false>(u); aH += up8<true>(u);
    }
    aL += shflx(aL, 16); aH += shflx(aH, 16);
    aL += shflx(aL, 32); aH += shflx(aH, 32);
    float wd = dinv[wid];
    float2 b0 = ((const float2*)bias)[q];        // b[2q], b[2q+1]
    float2 b1 = ((const float2*)bias)[q + 16];   // b[2q+32], b[2q+33]
    float v0 = fmaf(wd, aL.x, b0.x);  // f2q
    float v1 = fmaf(wd, aH.x, b0.y);  // f2q+1
    float v2 = fmaf(wd, aL.y, b1.x);  // f2q+32
    float v3 = fmaf(wd, aH.y, b1.y);  // f2q+33
    float m = fmaxf(fmaxf(v0, v1), fmaxf(v2, v3));
#pragma unroll
    for (int o = 1; o <= 8; o <<= 1) m = fmaxf(m, __shfl_xor(m, o, WAVE));
    float s = __expf(v0 - m) + __expf(v1 - m) + __expf(v2 - m) + __expf(v3 - m);
#pragma unroll
    for (int o = 1; o <= 8; o <<= 1) s += __shfl_xor(s, o, WAVE);
    float lg = __logf(s) + m;
    if (g == 0) {
        *(float2*)&out[(size_t)wid * 64 + 2 * q] = make_float2(v0 - lg, v1 - lg);
        *(float2*)&out[(size_t)wid * 64 + 32 + 2 * q] = make_float2(v2 - lg, v3 - lg);
    }
}

extern "C" void kernel_launch(void* const* d_in, const int* in_sizes, int n_in,
                              void* d_out, int out_size, void* d_ws, size_t ws_size,
                              hipStream_t stream) {
    const float* x  = (const float*)d_in[0];
    const float* W1 = (const float*)d_in[1];
    const float* b1 = (const float*)d_in[2];
    const float* W2 = (const float*)d_in[3];
    const float* b2 = (const float*)d_in[4];
    const int* edge = (const int*)d_in[5];

    const int N = in_sizes[0] / 256;
    const int E = in_sizes[5] / 2;
    const int* src = edge;
    const int* dst = edge + E;

    const int NBUCK = (N + 255) >> 8;  // <=512 (391 for N=100000)
    int mean = E / NBUCK;
    int CAP = mean + (int)(8.5 * __builtin_sqrt((double)mean)) + 32;
    CAP = (CAP + 63) & ~63;
    if (CAP > 14336) CAP = 14336;  // dynamic-LDS bound (56 KB)

    // ws layout (4B units): gcnt[512] | w1f[16384] | w2f[4096] | dinv[N] | rowstart[N]
    //   | rowend[N] | sorted[NBUCK*CAP] | h1f[N*32] | h2f[N*16] | agg1bf[N*64] (pairs alias)
    int*    gcnt     = (int*)d_ws;
    uint32* w1f      = (uint32*)(gcnt + 512);
    uint32* w2f      = w1f + 16384;
    float*  dinv     = (float*)(w2f + 4096);
    int*    rowstart = (int*)(dinv + N);
    int*    rowend   = rowstart + N;
    int*    sorted   = rowend + N;
    uint32* h1f      = (uint32*)(sorted + (size_t)NBUCK * CAP);  // N x 32 u32 (fp8)
    uint32* h2f      = h1f + (size_t)N * 32;                     // N x 16 u32 (fp8)
    uint32* agg1bf   = h2f + (size_t)N * 16;
    uint32* pairs    = agg1bf;  // dead before agg1bf is written
    float*  outp     = (float*)d_out;

    const int TB = 256;

    // 0) weight conversion to fragment-ordered bf16 (+ zero gcnt)
    convert_w_kernel<<<80, TB, 0, stream>>>(W1, W2, w1f, w2f, gcnt);

    // 1) CSR build via two-pass bucket sort (also produces dinv)
    binsort_kernel<<<(E + BIN_EPB - 1) / BIN_EPB, BIN_TB, 0, stream>>>(src, dst, gcnt, pairs, E, CAP);
    bucket_csr_kernel<<<NBUCK, 1024, (size_t)CAP * 4, stream>>>(pairs, gcnt, sorted, rowstart, rowend, dinv, N, CAP);

    // 2) h1f = fp8(dinv * (x @ W1))  [MFMA, LDS-staged A]
    gemm1_mfma<<<(N + 127) / 128, TB, 0, stream>>>(x, w1f, dinv, (unsigned short*)h1f, N);

    // 3) agg1bf = bf16(relu(dinv[d]*(self+sum) + b1)), lane-owns-slot fp8 gather
    agg1_kernel<<<(N * 64 + TB - 1) / TB, TB, 0, stream>>>(h1f, dinv, sorted, rowstart, rowend, b1, agg1bf, N);

    // 4) h2f = fp8(dinv * (agg1 @ W2))  [MFMA, bf16 A direct]
    gemm2_mfma<<<(N + 127) / 128, TB, 0, stream>>>(agg1bf, w2f, dinv, (unsigned short*)h2f, N);

    // 5) out = log_softmax(dinv[d]*(self+sum) + b2), lane-owns-slot fp8 gather
    agg2_ls_kernel<<<(N * 64 + TB - 1) / TB, TB, 0, stream>>>(h2f, dinv, sorted, rowstart, rowend, b2, outp, N);
}

// Round 14
// 220.416 us; speedup vs baseline: 1.0454x; 1.0454x over previous
//
#include <hip/hip_runtime.h>
#include <hip/hip_bf16.h>

#define WAVE 64
typedef unsigned int uint32;
typedef __attribute__((ext_vector_type(8))) short bf16x8;
typedef __attribute__((ext_vector_type(4))) float f32x4;
typedef __attribute__((ext_vector_type(2))) float f32x2;

// ---- bf16 helpers ----
__device__ inline uint32 f2bf(float f) {  // round-to-nearest-even, bits in low 16
    union { float f; uint32 u; } a; a.f = f;
    uint32 u = a.u;
    u += 0x7fffu + ((u >> 16) & 1u);
    return u >> 16;
}
__device__ inline uint32 packbf(float lo, float hi) { return f2bf(lo) | (f2bf(hi) << 16); }
__device__ inline short f2bfs(float f) { return (short)f2bf(f); }
__device__ inline f32x2 shflx(f32x2 v, int o) {
    v.x = __shfl_xor(v.x, o, WAVE);
    v.y = __shfl_xor(v.y, o, WAVE);
    return v;
}
// ---- fp8 e4m3 helpers (HW cvt, OCP on gfx950) ----
template <bool HI>
__device__ inline f32x2 up8(uint32 u) {  // bytes (0,1) or (2,3) -> {lo, hi} f32
    return __builtin_amdgcn_cvt_pk_f32_fp8((int)u, HI);
}
__device__ inline unsigned short pack8(float lo, float hi) {
    return (unsigned short)__builtin_amdgcn_cvt_pk_fp8_f32(lo, hi, 0, false);
}

// ---------------- W1/W2 -> fragment-ordered bf16 (+ gcnt zeroing) ----------------
__global__ void convert_w_kernel(const float* __restrict__ W1, const float* __restrict__ W2,
                                 uint32* __restrict__ w1f, uint32* __restrict__ w2f,
                                 int* __restrict__ gcnt) {
    int tid = blockIdx.x * blockDim.x + threadIdx.x;  // 0..20479
    if (tid < 256) gcnt[tid] = 0;
    if (tid < 16384) {
        int w = tid & 3, l = (tid >> 2) & 63, c = (tid >> 8) & 7, kc = tid >> 11;
        int q = l & 15, g = l >> 4;
        int k0 = kc * 32 + g * 8 + 2 * w;
        int n = c * 16 + q;
        w1f[tid] = packbf(W1[k0 * 128 + n], W1[(k0 + 1) * 128 + n]);
    } else if (tid < 16384 + 4096) {
        int t = tid - 16384;
        int w = t & 3, l = (t >> 2) & 63, c = (t >> 8) & 3, kc = t >> 10;
        int q = l & 15, g = l >> 4;
        int k0 = kc * 32 + g * 8 + 2 * w;
        int n = c * 16 + q;
        w2f[t] = packbf(W2[k0 * 64 + n], W2[(k0 + 1) * 64 + n]);
    }
}

// ================= CSR build: two-pass bucket sort =================
#define BIN_TB 1024
#define BIN_EPB 4096
__global__ __launch_bounds__(BIN_TB) void binsort_kernel(const int* __restrict__ src,
                                                         const int* __restrict__ dst,
                                                         int* __restrict__ gcnt,
                                                         uint32* __restrict__ pairs,
                                                         int E, int CAP) {
    __shared__ int hist[256];
    __shared__ int scan[256];
    __shared__ int lstart[256];
    __shared__ int gbase[256];
    __shared__ int lcur[256];
    __shared__ uint32 sp[BIN_EPB];
    __shared__ unsigned char sb[BIN_EPB];
    int tid = threadIdx.x;
    int base = blockIdx.x * BIN_EPB;
    if (tid < 256) hist[tid] = 0;
    __syncthreads();
    int b[4];
    uint32 pk[4];
    bool v[4];
#pragma unroll
    for (int j = 0; j < 4; ++j) {
        int e = base + tid + j * BIN_TB;
        v[j] = e < E;
        if (v[j]) {
            int s = src[e];
            int d = dst[e];
            b[j] = d >> 9;
            pk[j] = (uint32)s | ((uint32)(d & 511) << 17);
            atomicAdd(&hist[b[j]], 1);
        }
    }
    __syncthreads();
    if (tid < 256) scan[tid] = hist[tid];
    __syncthreads();
#pragma unroll
    for (int o = 1; o < 256; o <<= 1) {
        int t = 0;
        if (tid < 256 && tid >= o) t = scan[tid - o];
        __syncthreads();
        if (tid < 256) scan[tid] += t;
        __syncthreads();
    }
    if (tid < 256) {
        int st = scan[tid] - hist[tid];
        lstart[tid] = st;
        lcur[tid] = st;
        gbase[tid] = (hist[tid] > 0) ? (tid * CAP + atomicAdd(&gcnt[tid], hist[tid])) : 0;
    }
    __syncthreads();
#pragma unroll
    for (int j = 0; j < 4; ++j) {
        if (v[j]) {
            int p = atomicAdd(&lcur[b[j]], 1);
            sp[p] = pk[j];
            sb[p] = (unsigned char)b[j];
        }
    }
    __syncthreads();
    int total = scan[255];
    for (int i = tid; i < total; i += BIN_TB) {
        int bb = sb[i];
        pairs[gbase[bb] + (i - lstart[bb])] = sp[i];
    }
}

// Pass C: per-bucket counting sort staged in dynamic LDS, 1024 threads, coalesced flush.
__global__ __launch_bounds__(1024) void bucket_csr_kernel(const uint32* __restrict__ pairs,
                                                          const int* __restrict__ gcnt,
                                                          int* __restrict__ sorted,
                                                          int* __restrict__ rowstart,
                                                          int* __restrict__ rowend,
                                                          float* __restrict__ dinv,
                                                          int N, int CAP) {
    __shared__ int cnt[512];
    __shared__ int incl[512];
    __shared__ int cursor[512];
    extern __shared__ uint32 ssorted[];  // CAP entries
    int b = blockIdx.x;
    int tid = threadIdx.x;
    int ne = gcnt[b];
    if (ne > CAP) ne = CAP;
    const uint32* P = pairs + (size_t)b * CAP;
    if (tid < 512) cnt[tid] = 0;
    __syncthreads();
    for (int i = tid; i < ne; i += 1024) atomicAdd(&cnt[P[i] >> 17], 1);
    __syncthreads();
    int v = 0;
    if (tid < 512) { v = cnt[tid]; incl[tid] = v; }
    __syncthreads();
#pragma unroll
    for (int o = 1; o < 512; o <<= 1) {
        int t = 0;
        if (tid < 512 && tid >= o) t = incl[tid - o];
        __syncthreads();
        if (tid < 512) incl[tid] += t;
        __syncthreads();
    }
    int gbase = b * CAP;
    if (tid < 512) {
        int node = b * 512 + tid;
        if (node < N) {
            rowstart[node] = gbase + incl[tid] - v;
            rowend[node] = gbase + incl[tid];
            dinv[node] = rsqrtf(1.0f + (float)v);
        }
        cursor[tid] = incl[tid] - v;
    }
    __syncthreads();
    for (int i = tid; i < ne; i += 1024) {
        uint32 p = P[i];
        int ln = p >> 17;
        int r = atomicAdd(&cursor[ln], 1);
        ssorted[r] = p & 0x1FFFFu;
    }
    __syncthreads();
    for (int i = tid; i < ne; i += 1024) sorted[gbase + i] = (int)ssorted[i];
}

// ---------------- GEMM1 (MFMA): [N,256]fp32 @ W1F -> h1f fp8, u16 slot j = (f_j, f_j+64) ----------------
__global__ __launch_bounds__(256) void gemm1_mfma(const float* __restrict__ x,
                                                  const uint32* __restrict__ w1f,
                                                  const float* __restrict__ dinv,
                                                  unsigned short* __restrict__ h1f,  // N x 64 u16
                                                  int N) {
    const bf16x8* Bp = (const bf16x8*)w1f;
    int l = threadIdx.x & 63, w = threadIdx.x >> 6;
    int q = l & 15, g = l >> 4;
    int R = blockIdx.x * 128 + w * 32;
    f32x4 acc[2][8];
#pragma unroll
    for (int rt = 0; rt < 2; ++rt)
#pragma unroll
        for (int c = 0; c < 8; ++c) acc[rt][c] = (f32x4){0.f, 0.f, 0.f, 0.f};

#pragma unroll
    for (int kc = 0; kc < 8; ++kc) {
        bf16x8 b[8];
#pragma unroll
        for (int c = 0; c < 8; ++c) b[c] = Bp[(kc * 8 + c) * 64 + l];
#pragma unroll
        for (int rt = 0; rt < 2; ++rt) {
            int row = R + rt * 16 + q;
            row = row < N ? row : N - 1;
            const float* xr = x + (size_t)row * 256 + kc * 32 + g * 8;
            float4 xa = *(const float4*)xr;
            float4 xb = *(const float4*)(xr + 4);
            bf16x8 a;
            a[0] = f2bfs(xa.x); a[1] = f2bfs(xa.y); a[2] = f2bfs(xa.z); a[3] = f2bfs(xa.w);
            a[4] = f2bfs(xb.x); a[5] = f2bfs(xb.y); a[6] = f2bfs(xb.z); a[7] = f2bfs(xb.w);
#pragma unroll
            for (int c = 0; c < 8; ++c)
                acc[rt][c] = __builtin_amdgcn_mfma_f32_16x16x32_bf16(a, b[c], acc[rt][c], 0, 0, 0);
        }
    }
#pragma unroll
    for (int rt = 0; rt < 2; ++rt)
#pragma unroll
        for (int r = 0; r < 4; ++r) {
            int grow = R + rt * 16 + 4 * g + r;
            if (grow < N) {
                float wd = dinv[grow];
                unsigned short* orow = h1f + (size_t)grow * 64;
#pragma unroll
                for (int c = 0; c < 4; ++c)
                    orow[c * 16 + q] = pack8(acc[rt][c][r] * wd, acc[rt][c + 4][r] * wd);
            }
        }
}

// ---------------- layer-1 pull aggregation: lane-owns-slot, no cross-lane reduce ----------------
// h1f row = 32 u32 (128 B). Half-wave per edge: lane q in [0,32) loads u32 slot q.
// u32 slot q = feats (2q, 2q+64, 2q+1, 2q+65). Halves take alternate edges; one
// shfl_xor(32) combine at the end. Out: bf16 natural pairs (u32 k = feats 2k,2k+1).
__global__ __launch_bounds__(256) void agg1_kernel(const uint32* __restrict__ h1,  // N x 32 u32
                                                   const float* __restrict__ dinv,
                                                   const int* __restrict__ srt,
                                                   const int* __restrict__ rowstart,
                                                   const int* __restrict__ rowend,
                                                   const float* __restrict__ bias,
                                                   uint32* __restrict__ out,  // N x 64
                                                   int n) {
    int wid = (int)(((long)blockIdx.x * blockDim.x + threadIdx.x) >> 6);
    int lane = threadIdx.x & 63;
    if (wid >= n) return;
    int q = lane & 31;
    int half = lane >> 5;
    int start = rowstart[wid];
    int end = rowend[wid];
    f32x2 aL = {0.f, 0.f}, aH = {0.f, 0.f};  // aL=(f2q, f2q+64), aH=(f2q+1, f2q+65)
    if (half == 0) {  // self (already dinv-scaled)
        uint32 u = h1[(size_t)wid * 32 + q];
        aL = up8<false>(u); aH = up8<true>(u);
    }
    int e = start + half;
    for (; e + 6 < end; e += 8) {  // 4 edges in flight per half-wave
        int s0 = srt[e], s1 = srt[e + 2], s2 = srt[e + 4], s3 = srt[e + 6];
        uint32 u0 = h1[(size_t)s0 * 32 + q];
        uint32 u1 = h1[(size_t)s1 * 32 + q];
        uint32 u2 = h1[(size_t)s2 * 32 + q];
        uint32 u3 = h1[(size_t)s3 * 32 + q];
        aL += up8<false>(u0); aH += up8<true>(u0);
        aL += up8<false>(u1); aH += up8<true>(u1);
        aL += up8<false>(u2); aH += up8<true>(u2);
        aL += up8<false>(u3); aH += up8<true>(u3);
    }
    for (; e < end; e += 2) {
        uint32 u = h1[(size_t)srt[e] * 32 + q];
        aL += up8<false>(u); aH += up8<true>(u);
    }
    aL += shflx(aL, 32);
    aH += shflx(aH, 32);
    if (half == 0) {
        float wd = dinv[wid];
        float2 b0 = ((const float2*)bias)[q];        // b[2q], b[2q+1]
        float2 b1 = ((const float2*)bias)[q + 32];   // b[2q+64], b[2q+65]
        float v0 = fmaxf(fmaf(wd, aL.x, b0.x), 0.f); // f2q
        float v1 = fmaxf(fmaf(wd, aH.x, b0.y), 0.f); // f2q+1
        float v2 = fmaxf(fmaf(wd, aL.y, b1.x), 0.f); // f2q+64
        float v3 = fmaxf(fmaf(wd, aH.y, b1.y), 0.f); // f2q+65
        uint32* orow = out + (size_t)wid * 64;
        orow[q] = packbf(v0, v1);
        orow[32 + q] = packbf(v2, v3);
    }
}

// ---------------- GEMM2 (MFMA): [N,128]bf16 @ W2F -> h2f fp8, u16 slot j = (f_j, f_j+32) ----------------
__global__ __launch_bounds__(256) void gemm2_mfma(const uint32* __restrict__ hin,  // N x 64 bf16-pairs
                                                  const uint32* __restrict__ w2f,
                                                  const float* __restrict__ dinv,
                                                  unsigned short* __restrict__ h2f,  // N x 32 u16
                                                  int N) {
    const bf16x8* Bp = (const bf16x8*)w2f;
    const short* hs = (const short*)hin;
    int l = threadIdx.x & 63, w = threadIdx.x >> 6;
    int q = l & 15, g = l >> 4;
    int R = blockIdx.x * 128 + w * 32;
    f32x4 acc[2][4];
#pragma unroll
    for (int rt = 0; rt < 2; ++rt)
#pragma unroll
        for (int c = 0; c < 4; ++c) acc[rt][c] = (f32x4){0.f, 0.f, 0.f, 0.f};

#pragma unroll
    for (int kc = 0; kc < 4; ++kc) {
        bf16x8 b[4];
#pragma unroll
        for (int c = 0; c < 4; ++c) b[c] = Bp[(kc * 4 + c) * 64 + l];
#pragma unroll
        for (int rt = 0; rt < 2; ++rt) {
            int row = R + rt * 16 + q;
            row = row < N ? row : N - 1;
            bf16x8 a = *(const bf16x8*)(hs + (size_t)row * 128 + kc * 32 + g * 8);
#pragma unroll
            for (int c = 0; c < 4; ++c)
                acc[rt][c] = __builtin_amdgcn_mfma_f32_16x16x32_bf16(a, b[c], acc[rt][c], 0, 0, 0);
        }
    }
#pragma unroll
    for (int rt = 0; rt < 2; ++rt)
#pragma unroll
        for (int r = 0; r < 4; ++r) {
            int grow = R + rt * 16 + 4 * g + r;
            if (grow < N) {
                float wd = dinv[grow];
                unsigned short* orow = h2f + (size_t)grow * 32;
#pragma unroll
                for (int c = 0; c < 2; ++c)
                    orow[c * 16 + q] = pack8(acc[rt][c][r] * wd, acc[rt][c + 2][r] * wd);
            }
        }
}

// ---------------- layer-2 pull aggregation + log_softmax: lane-owns-slot ----------------
// h2f row = 16 u32 (64 B). 16-lane group per edge: lane q in [0,16) loads u32 slot q.
// u32 slot q = feats (2q, 2q+32, 2q+1, 2q+33). 4 groups take edge strides; 2-level combine.
__global__ __launch_bounds__(256) void agg2_ls_kernel(const uint32* __restrict__ h2,  // N x 16 u32
                                                      const float* __restrict__ dinv,
                                                      const int* __restrict__ srt,
                                                      const int* __restrict__ rowstart,
                                                      const int* __restrict__ rowend,
                                                      const float* __restrict__ bias,
                                                      float* __restrict__ out, int n) {
    int wid = (int)(((long)blockIdx.x * blockDim.x + threadIdx.x) >> 6);
    int lane = threadIdx.x & 63;
    if (wid >= n) return;
    int q = lane & 15;
    int g = lane >> 4;
    int start = rowstart[wid];
    int end = rowend[wid];
    f32x2 aL = {0.f, 0.f}, aH = {0.f, 0.f};  // aL=(f2q, f2q+32), aH=(f2q+1, f2q+33)
    if (g == 0) {  // self
        uint32 u = h2[(size_t)wid * 16 + q];
        aL = up8<false>(u); aH = up8<true>(u);
    }
    int e = start + g;
    for (; e + 12 < end; e += 16) {  // 4 edges in flight per group
        int s0 = srt[e], s1 = srt[e + 4], s2 = srt[e + 8], s3 = srt[e + 12];
        uint32 u0 = h2[(size_t)s0 * 16 + q];
        uint32 u1 = h2[(size_t)s1 * 16 + q];
        uint32 u2 = h2[(size_t)s2 * 16 + q];
        uint32 u3 = h2[(size_t)s3 * 16 + q];
        aL += up8<false>(u0); aH += up8<true>(u0);
        aL += up8<false>(u1); aH += up8<true>(u1);
        aL += up8<false>(u2); aH += up8<true>(u2);
        aL += up8<false>(u3); aH += up8<true>(u3);
    }
    for (; e < end; e += 4) {
        uint32 u = h2[(size_t)srt[e] * 16 + q];
        aL += up8<false>(u); aH += up8<true>(u);
    }
    aL += shflx(aL, 16); aH += shflx(aH, 16);
    aL += shflx(aL, 32); aH += shflx(aH, 32);
    float wd = dinv[wid];
    float2 b0 = ((const float2*)bias)[q];        // b[2q], b[2q+1]
    float2 b1 = ((const float2*)bias)[q + 16];   // b[2q+32], b[2q+33]
    float v0 = fmaf(wd, aL.x, b0.x);  // f2q
    float v1 = fmaf(wd, aH.x, b0.y);  // f2q+1
    float v2 = fmaf(wd, aL.y, b1.x);  // f2q+32
    float v3 = fmaf(wd, aH.y, b1.y);  // f2q+33
    float m = fmaxf(fmaxf(v0, v1), fmaxf(v2, v3));
#pragma unroll
    for (int o = 1; o <= 8; o <<= 1) m = fmaxf(m, __shfl_xor(m, o, WAVE));
    float s = __expf(v0 - m) + __expf(v1 - m) + __expf(v2 - m) + __expf(v3 - m);
#pragma unroll
    for (int o = 1; o <= 8; o <<= 1) s += __shfl_xor(s, o, WAVE);
    float lg = __logf(s) + m;
    if (g == 0) {
        *(float2*)&out[(size_t)wid * 64 + 2 * q] = make_float2(v0 - lg, v1 - lg);
        *(float2*)&out[(size_t)wid * 64 + 32 + 2 * q] = make_float2(v2 - lg, v3 - lg);
    }
}

extern "C" void kernel_launch(void* const* d_in, const int* in_sizes, int n_in,
                              void* d_out, int out_size, void* d_ws, size_t ws_size,
                              hipStream_t stream) {
    const float* x  = (const float*)d_in[0];
    const float* W1 = (const float*)d_in[1];
    const float* b1 = (const float*)d_in[2];
    const float* W2 = (const float*)d_in[3];
    const float* b2 = (const float*)d_in[4];
    const int* edge = (const int*)d_in[5];

    const int N = in_sizes[0] / 256;
    const int E = in_sizes[5] / 2;
    const int* src = edge;
    const int* dst = edge + E;

    const int NBUCK = (N + 511) >> 9;  // <=256
    int mean = E / NBUCK;
    int CAP = mean + (int)(8.5 * __builtin_sqrt((double)mean)) + 32;
    CAP = (CAP + 63) & ~63;
    if (CAP > 36864) CAP = 36864;  // LDS flush buffer bound (144 KB)

    // ws layout (4B units): gcnt[256] | w1f[16384] | w2f[4096] | dinv[N] | rowstart[N]
    //   | rowend[N] | sorted[NBUCK*CAP] | h1f[N*32] | h2f[N*16] | agg1bf[N*64] (pairs alias)
    int*    gcnt     = (int*)d_ws;
    uint32* w1f      = (uint32*)(gcnt + 256);
    uint32* w2f      = w1f + 16384;
    float*  dinv     = (float*)(w2f + 4096);
    int*    rowstart = (int*)(dinv + N);
    int*    rowend   = rowstart + N;
    int*    sorted   = rowend + N;
    uint32* h1f      = (uint32*)(sorted + (size_t)NBUCK * CAP);  // N x 32 u32 (fp8)
    uint32* h2f      = h1f + (size_t)N * 32;                     // N x 16 u32 (fp8)
    uint32* agg1bf   = h2f + (size_t)N * 16;
    uint32* pairs    = agg1bf;  // dead before agg1bf is written
    float*  outp     = (float*)d_out;

    const int TB = 256;

    // 0) weight conversion to fragment-ordered bf16 (+ zero gcnt)
    convert_w_kernel<<<80, TB, 0, stream>>>(W1, W2, w1f, w2f, gcnt);

    // 1) CSR build via two-pass bucket sort (also produces dinv)
    binsort_kernel<<<(E + BIN_EPB - 1) / BIN_EPB, BIN_TB, 0, stream>>>(src, dst, gcnt, pairs, E, CAP);
    bucket_csr_kernel<<<NBUCK, 1024, (size_t)CAP * 4, stream>>>(pairs, gcnt, sorted, rowstart, rowend, dinv, N, CAP);

    // 2) h1f = fp8(dinv * (x @ W1))  [MFMA]
    gemm1_mfma<<<(N + 127) / 128, TB, 0, stream>>>(x, w1f, dinv, (unsigned short*)h1f, N);

    // 3) agg1bf = bf16(relu(dinv[d]*(self+sum) + b1)), lane-owns-slot fp8 gather
    agg1_kernel<<<(N * 64 + TB - 1) / TB, TB, 0, stream>>>(h1f, dinv, sorted, rowstart, rowend, b1, agg1bf, N);

    // 4) h2f = fp8(dinv * (agg1 @ W2))  [MFMA, bf16 A direct]
    gemm2_mfma<<<(N + 127) / 128, TB, 0, stream>>>(agg1bf, w2f, dinv, (unsigned short*)h2f, N);

    // 5) out = log_softmax(dinv[d]*(self+sum) + b2), lane-owns-slot fp8 gather
    agg2_ls_kernel<<<(N * 64 + TB - 1) / TB, TB, 0, stream>>>(h2f, dinv, sorted, rowstart, rowend, b2, outp, N);
}

// Round 15
// 219.224 us; speedup vs baseline: 1.0511x; 1.0054x over previous
//
#include <hip/hip_runtime.h>
#include <hip/hip_bf16.h>

#define WAVE 64
typedef unsigned int uint32;
typedef __attribute__((ext_vector_type(8))) short bf16x8;
typedef __attribute__((ext_vector_type(4))) float f32x4;
typedef __attribute__((ext_vector_type(2))) float f32x2;

// ---- bf16 helpers ----
__device__ inline uint32 f2bf(float f) {  // round-to-nearest-even, bits in low 16
    union { float f; uint32 u; } a; a.f = f;
    uint32 u = a.u;
    u += 0x7fffu + ((u >> 16) & 1u);
    return u >> 16;
}
__device__ inline uint32 packbf(float lo, float hi) { return f2bf(lo) | (f2bf(hi) << 16); }
__device__ inline f32x2 shflx(f32x2 v, int o) {
    v.x = __shfl_xor(v.x, o, WAVE);
    v.y = __shfl_xor(v.y, o, WAVE);
    return v;
}
// ---- fp8 e4m3 helpers (HW cvt, OCP on gfx950) ----
template <bool HI>
__device__ inline f32x2 up8(uint32 u) {  // bytes (0,1) or (2,3) -> {lo, hi} f32
    return __builtin_amdgcn_cvt_pk_f32_fp8((int)u, HI);
}
__device__ inline unsigned short pack8(float lo, float hi) {
    return (unsigned short)__builtin_amdgcn_cvt_pk_fp8_f32(lo, hi, 0, false);
}

// ---------------- W1/W2 -> fragment-ordered bf16 (+ gcnt zeroing) ----------------
__global__ void convert_w_kernel(const float* __restrict__ W1, const float* __restrict__ W2,
                                 uint32* __restrict__ w1f, uint32* __restrict__ w2f,
                                 int* __restrict__ gcnt) {
    int tid = blockIdx.x * blockDim.x + threadIdx.x;  // 0..20479
    if (tid < 256) gcnt[tid] = 0;
    if (tid < 16384) {
        int w = tid & 3, l = (tid >> 2) & 63, c = (tid >> 8) & 7, kc = tid >> 11;
        int q = l & 15, g = l >> 4;
        int k0 = kc * 32 + g * 8 + 2 * w;
        int n = c * 16 + q;
        w1f[tid] = packbf(W1[k0 * 128 + n], W1[(k0 + 1) * 128 + n]);
    } else if (tid < 16384 + 4096) {
        int t = tid - 16384;
        int w = t & 3, l = (t >> 2) & 63, c = (t >> 8) & 3, kc = t >> 10;
        int q = l & 15, g = l >> 4;
        int k0 = kc * 32 + g * 8 + 2 * w;
        int n = c * 16 + q;
        w2f[t] = packbf(W2[k0 * 64 + n], W2[(k0 + 1) * 64 + n]);
    }
}

// ================= CSR build: two-pass bucket sort =================
#define BIN_TB 1024
#define BIN_EPB 4096
__global__ __launch_bounds__(BIN_TB) void binsort_kernel(const int* __restrict__ src,
                                                         const int* __restrict__ dst,
                                                         int* __restrict__ gcnt,
                                                         uint32* __restrict__ pairs,
                                                         int E, int CAP) {
    __shared__ int hist[256];
    __shared__ int scan[256];
    __shared__ int lstart[256];
    __shared__ int gbase[256];
    __shared__ int lcur[256];
    __shared__ uint32 sp[BIN_EPB];
    __shared__ unsigned char sb[BIN_EPB];
    int tid = threadIdx.x;
    int base = blockIdx.x * BIN_EPB;
    if (tid < 256) hist[tid] = 0;
    __syncthreads();
    int b[4];
    uint32 pk[4];
    bool v[4];
#pragma unroll
    for (int j = 0; j < 4; ++j) {
        int e = base + tid + j * BIN_TB;
        v[j] = e < E;
        if (v[j]) {
            int s = src[e];
            int d = dst[e];
            b[j] = d >> 9;
            pk[j] = (uint32)s | ((uint32)(d & 511) << 17);
            atomicAdd(&hist[b[j]], 1);
        }
    }
    __syncthreads();
    if (tid < 256) scan[tid] = hist[tid];
    __syncthreads();
#pragma unroll
    for (int o = 1; o < 256; o <<= 1) {
        int t = 0;
        if (tid < 256 && tid >= o) t = scan[tid - o];
        __syncthreads();
        if (tid < 256) scan[tid] += t;
        __syncthreads();
    }
    if (tid < 256) {
        int st = scan[tid] - hist[tid];
        lstart[tid] = st;
        lcur[tid] = st;
        gbase[tid] = (hist[tid] > 0) ? (tid * CAP + atomicAdd(&gcnt[tid], hist[tid])) : 0;
    }
    __syncthreads();
#pragma unroll
    for (int j = 0; j < 4; ++j) {
        if (v[j]) {
            int p = atomicAdd(&lcur[b[j]], 1);
            sp[p] = pk[j];
            sb[p] = (unsigned char)b[j];
        }
    }
    __syncthreads();
    int total = scan[255];
    for (int i = tid; i < total; i += BIN_TB) {
        int bb = sb[i];
        pairs[gbase[bb] + (i - lstart[bb])] = sp[i];
    }
}

// Pass C: per-bucket counting sort staged in dynamic LDS, 1024 threads, coalesced flush.
__global__ __launch_bounds__(1024) void bucket_csr_kernel(const uint32* __restrict__ pairs,
                                                          const int* __restrict__ gcnt,
                                                          int* __restrict__ sorted,
                                                          int* __restrict__ rowstart,
                                                          int* __restrict__ rowend,
                                                          float* __restrict__ dinv,
                                                          int N, int CAP) {
    __shared__ int cnt[512];
    __shared__ int incl[512];
    __shared__ int cursor[512];
    extern __shared__ uint32 ssorted[];  // CAP entries
    int b = blockIdx.x;
    int tid = threadIdx.x;
    int ne = gcnt[b];
    if (ne > CAP) ne = CAP;
    const uint32* P = pairs + (size_t)b * CAP;
    if (tid < 512) cnt[tid] = 0;
    __syncthreads();
    for (int i = tid; i < ne; i += 1024) atomicAdd(&cnt[P[i] >> 17], 1);
    __syncthreads();
    int v = 0;
    if (tid < 512) { v = cnt[tid]; incl[tid] = v; }
    __syncthreads();
#pragma unroll
    for (int o = 1; o < 512; o <<= 1) {
        int t = 0;
        if (tid < 512 && tid >= o) t = incl[tid - o];
        __syncthreads();
        if (tid < 512) incl[tid] += t;
        __syncthreads();
    }
    int gbase = b * CAP;
    if (tid < 512) {
        int node = b * 512 + tid;
        if (node < N) {
            rowstart[node] = gbase + incl[tid] - v;
            rowend[node] = gbase + incl[tid];
            dinv[node] = rsqrtf(1.0f + (float)v);
        }
        cursor[tid] = incl[tid] - v;
    }
    __syncthreads();
    for (int i = tid; i < ne; i += 1024) {
        uint32 p = P[i];
        int ln = p >> 17;
        int r = atomicAdd(&cursor[ln], 1);
        ssorted[r] = p & 0x1FFFFu;
    }
    __syncthreads();
    for (int i = tid; i < ne; i += 1024) sorted[gbase + i] = (int)ssorted[i];
}

// ---------------- GEMM1 (MFMA, LDS-staged): [N,256]fp32 @ W1F -> h1f fp8 ----------------
// Per kc: stage 128 rows x 32 k-floats as bf16 into LDS (coalesced global loads),
// A fragment = one ds_read_b128. LDS row stride 40 bf16 (80 B, 16B-aligned frags).
__global__ __launch_bounds__(256) void gemm1_mfma(const float* __restrict__ x,
                                                  const uint32* __restrict__ w1f,
                                                  const float* __restrict__ dinv,
                                                  unsigned short* __restrict__ h1f,  // N x 64 u16
                                                  int N) {
    __shared__ short xs[128 * 40];  // 10 KB
    const bf16x8* Bp = (const bf16x8*)w1f;
    int tid = threadIdx.x;
    int l = tid & 63, w = tid >> 6;
    int q = l & 15, g = l >> 4;
    int R = blockIdx.x * 128;
    int rloc = w * 32;
    f32x4 acc[2][8];
#pragma unroll
    for (int rt = 0; rt < 2; ++rt)
#pragma unroll
        for (int c = 0; c < 8; ++c) acc[rt][c] = (f32x4){0.f, 0.f, 0.f, 0.f};

    int srow = tid >> 1;
    int scol = (tid & 1) * 16;
    long grow_s = R + srow;
    if (grow_s > N - 1) grow_s = N - 1;
    const float* xbase = x + grow_s * 256 + scol;
    uint2* sdst = (uint2*)&xs[srow * 40 + scol];

#pragma unroll
    for (int kc = 0; kc < 8; ++kc) {
        __syncthreads();
        {
            const float4* xp = (const float4*)(xbase + kc * 32);
            float4 f0 = xp[0], f1 = xp[1], f2 = xp[2], f3 = xp[3];
            sdst[0] = make_uint2(packbf(f0.x, f0.y), packbf(f0.z, f0.w));
            sdst[1] = make_uint2(packbf(f1.x, f1.y), packbf(f1.z, f1.w));
            sdst[2] = make_uint2(packbf(f2.x, f2.y), packbf(f2.z, f2.w));
            sdst[3] = make_uint2(packbf(f3.x, f3.y), packbf(f3.z, f3.w));
        }
        __syncthreads();
        bf16x8 b[8];
#pragma unroll
        for (int c = 0; c < 8; ++c) b[c] = Bp[(kc * 8 + c) * 64 + l];
#pragma unroll
        for (int rt = 0; rt < 2; ++rt) {
            bf16x8 a = *(const bf16x8*)&xs[(rloc + rt * 16 + q) * 40 + g * 8];
#pragma unroll
            for (int c = 0; c < 8; ++c)
                acc[rt][c] = __builtin_amdgcn_mfma_f32_16x16x32_bf16(a, b[c], acc[rt][c], 0, 0, 0);
        }
    }
#pragma unroll
    for (int rt = 0; rt < 2; ++rt)
#pragma unroll
        for (int r = 0; r < 4; ++r) {
            int grow = R + rloc + rt * 16 + 4 * g + r;
            if (grow < N) {
                float wd = dinv[grow];
                unsigned short* orow = h1f + (size_t)grow * 64;
#pragma unroll
                for (int c = 0; c < 4; ++c)
                    orow[c * 16 + q] = pack8(acc[rt][c][r] * wd, acc[rt][c + 4][r] * wd);
            }
        }
}

// ---------------- layer-1 pull aggregation: lane-owns-slot, no cross-lane reduce ----------------
// h1f row = 32 u32 (128 B). Half-wave per edge: lane q in [0,32) loads u32 slot q.
// u32 slot q = feats (2q, 2q+64, 2q+1, 2q+65). Halves take alternate edges; one
// shfl_xor(32) combine at the end. Out: bf16 natural pairs (u32 k = feats 2k,2k+1).
__global__ __launch_bounds__(256) void agg1_kernel(const uint32* __restrict__ h1,  // N x 32 u32
                                                   const float* __restrict__ dinv,
                                                   const int* __restrict__ srt,
                                                   const int* __restrict__ rowstart,
                                                   const int* __restrict__ rowend,
                                                   const float* __restrict__ bias,
                                                   uint32* __restrict__ out,  // N x 64
                                                   int n) {
    int wid = (int)(((long)blockIdx.x * blockDim.x + threadIdx.x) >> 6);
    int lane = threadIdx.x & 63;
    if (wid >= n) return;
    int q = lane & 31;
    int half = lane >> 5;
    int start = rowstart[wid];
    int end = rowend[wid];
    f32x2 aL = {0.f, 0.f}, aH = {0.f, 0.f};  // aL=(f2q, f2q+64), aH=(f2q+1, f2q+65)
    if (half == 0) {  // self (already dinv-scaled)
        uint32 u = h1[(size_t)wid * 32 + q];
        aL = up8<false>(u); aH = up8<true>(u);
    }
    int e = start + half;
    for (; e + 6 < end; e += 8) {  // 4 edges in flight per half-wave
        int s0 = srt[e], s1 = srt[e + 2], s2 = srt[e + 4], s3 = srt[e + 6];
        uint32 u0 = h1[(size_t)s0 * 32 + q];
        uint32 u1 = h1[(size_t)s1 * 32 + q];
        uint32 u2 = h1[(size_t)s2 * 32 + q];
        uint32 u3 = h1[(size_t)s3 * 32 + q];
        aL += up8<false>(u0); aH += up8<true>(u0);
        aL += up8<false>(u1); aH += up8<true>(u1);
        aL += up8<false>(u2); aH += up8<true>(u2);
        aL += up8<false>(u3); aH += up8<true>(u3);
    }
    for (; e < end; e += 2) {
        uint32 u = h1[(size_t)srt[e] * 32 + q];
        aL += up8<false>(u); aH += up8<true>(u);
    }
    aL += shflx(aL, 32);
    aH += shflx(aH, 32);
    if (half == 0) {
        float wd = dinv[wid];
        float2 b0 = ((const float2*)bias)[q];        // b[2q], b[2q+1]
        float2 b1 = ((const float2*)bias)[q + 32];   // b[2q+64], b[2q+65]
        float v0 = fmaxf(fmaf(wd, aL.x, b0.x), 0.f); // f2q
        float v1 = fmaxf(fmaf(wd, aH.x, b0.y), 0.f); // f2q+1
        float v2 = fmaxf(fmaf(wd, aL.y, b1.x), 0.f); // f2q+64
        float v3 = fmaxf(fmaf(wd, aH.y, b1.y), 0.f); // f2q+65
        uint32* orow = out + (size_t)wid * 64;
        orow[q] = packbf(v0, v1);
        orow[32 + q] = packbf(v2, v3);
    }
}

// ---------------- GEMM2 (MFMA): [N,128]bf16 @ W2F -> h2f fp8, u16 slot j = (f_j, f_j+32) ----------------
__global__ __launch_bounds__(256) void gemm2_mfma(const uint32* __restrict__ hin,  // N x 64 bf16-pairs
                                                  const uint32* __restrict__ w2f,
                                                  const float* __restrict__ dinv,
                                                  unsigned short* __restrict__ h2f,  // N x 32 u16
                                                  int N) {
    const bf16x8* Bp = (const bf16x8*)w2f;
    const short* hs = (const short*)hin;
    int l = threadIdx.x & 63, w = threadIdx.x >> 6;
    int q = l & 15, g = l >> 4;
    int R = blockIdx.x * 128 + w * 32;
    f32x4 acc[2][4];
#pragma unroll
    for (int rt = 0; rt < 2; ++rt)
#pragma unroll
        for (int c = 0; c < 4; ++c) acc[rt][c] = (f32x4){0.f, 0.f, 0.f, 0.f};

#pragma unroll
    for (int kc = 0; kc < 4; ++kc) {
        bf16x8 b[4];
#pragma unroll
        for (int c = 0; c < 4; ++c) b[c] = Bp[(kc * 4 + c) * 64 + l];
#pragma unroll
        for (int rt = 0; rt < 2; ++rt) {
            int row = R + rt * 16 + q;
            row = row < N ? row : N - 1;
            bf16x8 a = *(const bf16x8*)(hs + (size_t)row * 128 + kc * 32 + g * 8);
#pragma unroll
            for (int c = 0; c < 4; ++c)
                acc[rt][c] = __builtin_amdgcn_mfma_f32_16x16x32_bf16(a, b[c], acc[rt][c], 0, 0, 0);
        }
    }
#pragma unroll
    for (int rt = 0; rt < 2; ++rt)
#pragma unroll
        for (int r = 0; r < 4; ++r) {
            int grow = R + rt * 16 + 4 * g + r;
            if (grow < N) {
                float wd = dinv[grow];
                unsigned short* orow = h2f + (size_t)grow * 32;
#pragma unroll
                for (int c = 0; c < 2; ++c)
                    orow[c * 16 + q] = pack8(acc[rt][c][r] * wd, acc[rt][c + 2][r] * wd);
            }
        }
}

// ---------------- layer-2 pull aggregation + log_softmax: lane-owns-slot ----------------
// h2f row = 16 u32 (64 B). 16-lane group per edge: lane q in [0,16) loads u32 slot q.
// u32 slot q = feats (2q, 2q+32, 2q+1, 2q+33). 4 groups take edge strides; 2-level combine.
__global__ __launch_bounds__(256) void agg2_ls_kernel(const uint32* __restrict__ h2,  // N x 16 u32
                                                      const float* __restrict__ dinv,
                                                      const int* __restrict__ srt,
                                                      const int* __restrict__ rowstart,
                                                      const int* __restrict__ rowend,
                                                      const float* __restrict__ bias,
                                                      float* __restrict__ out, int n) {
    int wid = (int)(((long)blockIdx.x * blockDim.x + threadIdx.x) >> 6);
    int lane = threadIdx.x & 63;
    if (wid >= n) return;
    int q = lane & 15;
    int g = lane >> 4;
    int start = rowstart[wid];
    int end = rowend[wid];
    f32x2 aL = {0.f, 0.f}, aH = {0.f, 0.f};  // aL=(f2q, f2q+32), aH=(f2q+1, f2q+33)
    if (g == 0) {  // self
        uint32 u = h2[(size_t)wid * 16 + q];
        aL = up8<false>(u); aH = up8<true>(u);
    }
    int e = start + g;
    for (; e + 12 < end; e += 16) {  // 4 edges in flight per group
        int s0 = srt[e], s1 = srt[e + 4], s2 = srt[e + 8], s3 = srt[e + 12];
        uint32 u0 = h2[(size_t)s0 * 16 + q];
        uint32 u1 = h2[(size_t)s1 * 16 + q];
        uint32 u2 = h2[(size_t)s2 * 16 + q];
        uint32 u3 = h2[(size_t)s3 * 16 + q];
        aL += up8<false>(u0); aH += up8<true>(u0);
        aL += up8<false>(u1); aH += up8<true>(u1);
        aL += up8<false>(u2); aH += up8<true>(u2);
        aL += up8<false>(u3); aH += up8<true>(u3);
    }
    for (; e < end; e += 4) {
        uint32 u = h2[(size_t)srt[e] * 16 + q];
        aL += up8<false>(u); aH += up8<true>(u);
    }
    aL += shflx(aL, 16); aH += shflx(aH, 16);
    aL += shflx(aL, 32); aH += shflx(aH, 32);
    float wd = dinv[wid];
    float2 b0 = ((const float2*)bias)[q];        // b[2q], b[2q+1]
    float2 b1 = ((const float2*)bias)[q + 16];   // b[2q+32], b[2q+33]
    float v0 = fmaf(wd, aL.x, b0.x);  // f2q
    float v1 = fmaf(wd, aH.x, b0.y);  // f2q+1
    float v2 = fmaf(wd, aL.y, b1.x);  // f2q+32
    float v3 = fmaf(wd, aH.y, b1.y);  // f2q+33
    float m = fmaxf(fmaxf(v0, v1), fmaxf(v2, v3));
#pragma unroll
    for (int o = 1; o <= 8; o <<= 1) m = fmaxf(m, __shfl_xor(m, o, WAVE));
    float s = __expf(v0 - m) + __expf(v1 - m) + __expf(v2 - m) + __expf(v3 - m);
#pragma unroll
    for (int o = 1; o <= 8; o <<= 1) s += __shfl_xor(s, o, WAVE);
    float lg = __logf(s) + m;
    if (g == 0) {
        *(float2*)&out[(size_t)wid * 64 + 2 * q] = make_float2(v0 - lg, v1 - lg);
        *(float2*)&out[(size_t)wid * 64 + 32 + 2 * q] = make_float2(v2 - lg, v3 - lg);
    }
}

extern "C" void kernel_launch(void* const* d_in, const int* in_sizes, int n_in,
                              void* d_out, int out_size, void* d_ws, size_t ws_size,
                              hipStream_t stream) {
    const float* x  = (const float*)d_in[0];
    const float* W1 = (const float*)d_in[1];
    const float* b1 = (const float*)d_in[2];
    const float* W2 = (const float*)d_in[3];
    const float* b2 = (const float*)d_in[4];
    const int* edge = (const int*)d_in[5];

    const int N = in_sizes[0] / 256;
    const int E = in_sizes[5] / 2;
    const int* src = edge;
    const int* dst = edge + E;

    const int NBUCK = (N + 511) >> 9;  // <=256
    int mean = E / NBUCK;
    int CAP = mean + (int)(8.5 * __builtin_sqrt((double)mean)) + 32;
    CAP = (CAP + 63) & ~63;
    if (CAP > 36864) CAP = 36864;  // LDS flush buffer bound (144 KB)

    // ws layout (4B units): gcnt[256] | w1f[16384] | w2f[4096] | dinv[N] | rowstart[N]
    //   | rowend[N] | sorted[NBUCK*CAP] | h1f[N*32] | h2f[N*16] | agg1bf[N*64] (pairs alias)
    int*    gcnt     = (int*)d_ws;
    uint32* w1f      = (uint32*)(gcnt + 256);
    uint32* w2f      = w1f + 16384;
    float*  dinv     = (float*)(w2f + 4096);
    int*    rowstart = (int*)(dinv + N);
    int*    rowend   = rowstart + N;
    int*    sorted   = rowend + N;
    uint32* h1f      = (uint32*)(sorted + (size_t)NBUCK * CAP);  // N x 32 u32 (fp8)
    uint32* h2f      = h1f + (size_t)N * 32;                     // N x 16 u32 (fp8)
    uint32* agg1bf   = h2f + (size_t)N * 16;
    uint32* pairs    = agg1bf;  // dead before agg1bf is written
    float*  outp     = (float*)d_out;

    const int TB = 256;

    // 0) weight conversion to fragment-ordered bf16 (+ zero gcnt)
    convert_w_kernel<<<80, TB, 0, stream>>>(W1, W2, w1f, w2f, gcnt);

    // 1) CSR build via two-pass bucket sort (also produces dinv)
    binsort_kernel<<<(E + BIN_EPB - 1) / BIN_EPB, BIN_TB, 0, stream>>>(src, dst, gcnt, pairs, E, CAP);
    bucket_csr_kernel<<<NBUCK, 1024, (size_t)CAP * 4, stream>>>(pairs, gcnt, sorted, rowstart, rowend, dinv, N, CAP);

    // 2) h1f = fp8(dinv * (x @ W1))  [MFMA, LDS-staged A]
    gemm1_mfma<<<(N + 127) / 128, TB, 0, stream>>>(x, w1f, dinv, (unsigned short*)h1f, N);

    // 3) agg1bf = bf16(relu(dinv[d]*(self+sum) + b1)), lane-owns-slot fp8 gather
    agg1_kernel<<<(N * 64 + TB - 1) / TB, TB, 0, stream>>>(h1f, dinv, sorted, rowstart, rowend, b1, agg1bf, N);

    // 4) h2f = fp8(dinv * (agg1 @ W2))  [MFMA, bf16 A direct]
    gemm2_mfma<<<(N + 127) / 128, TB, 0, stream>>>(agg1bf, w2f, dinv, (unsigned short*)h2f, N);

    // 5) out = log_softmax(dinv[d]*(self+sum) + b2), lane-owns-slot fp8 gather
    agg2_ls_kernel<<<(N * 64 + TB - 1) / TB, TB, 0, stream>>>(h2f, dinv, sorted, rowstart, rowend, b2, outp, N);
}